// Round 2
// baseline (761.032 us; speedup 1.0000x reference)
//
#include <hip/hip_runtime.h>

#define DEV __device__ __forceinline__

constexpr int B_  = 4;
constexpr int C_  = 256;
constexpr int C8_ = 32;
constexpr int N_  = 4096;   // 64*64

using u16 = unsigned short;
using u32 = unsigned int;

DEV float bflo(u32 u) { return __uint_as_float(u << 16); }
DEV float bfhi(u32 u) { return __uint_as_float(u & 0xffff0000u); }
DEV u16   f2bf(float f) {
  u32 i = __float_as_uint(f);
  i += 0x7fffu + ((i >> 16) & 1u);   // round-to-nearest-even
  return (u16)(i >> 16);
}

// ---------------------------------------------------------------------------
// Fused q/k/v 1x1-conv projections (f32 inputs).
//   q[b,d,n] -> f32 (B,C8,N);  k[b,d,n] -> f32 (B,C8,N);  v -> bf16 (B,N,C)
// grid (N/512, 20, B), block 256.  blockIdx.y: 0-1 q, 2-3 k, 4-19 v (16 d each)
// ---------------------------------------------------------------------------
__global__ __launch_bounds__(256) void qkv_proj(
    const float* __restrict__ x,
    const float* __restrict__ Wq, const float* __restrict__ bq,
    const float* __restrict__ Wk, const float* __restrict__ bk,
    const float* __restrict__ Wv, const float* __restrict__ bv,
    float* __restrict__ qb, float* __restrict__ kb, u16* __restrict__ vb)
{
  __shared__ __align__(16) float wl[C_][16];
  __shared__ float bl[16];
  const int tid = threadIdx.x;
  const int b   = blockIdx.z;
  const int yc  = blockIdx.y;

  const float *W, *bias;
  float* outf = nullptr;
  int d0, mode;
  if (yc < 2)      { W = Wq; bias = bq; d0 = yc * 16;       outf = qb; mode = 0; }
  else if (yc < 4) { W = Wk; bias = bk; d0 = (yc - 2) * 16; outf = kb; mode = 0; }
  else             { W = Wv; bias = bv; d0 = (yc - 4) * 16; mode = 1; }

  for (int idx = tid; idx < C_ * 16; idx += 256) {
    int r = idx >> 8, c = idx & 255;
    wl[c][r] = W[(d0 + r) * C_ + c];
  }
  if (tid < 16) bl[tid] = bias[d0 + tid];
  __syncthreads();

  const int n = blockIdx.x * 512 + tid * 2;
  float a0[16], a1[16];
  #pragma unroll
  for (int r = 0; r < 16; ++r) { a0[r] = 0.f; a1[r] = 0.f; }

  const float* xp = x + (size_t)b * C_ * N_ + n;
  for (int c = 0; c < C_; ++c) {
    float2 xv = *(const float2*)(xp + (size_t)c * N_);
    #pragma unroll
    for (int r = 0; r < 16; ++r) {
      float w = wl[c][r];
      a0[r] += w * xv.x;
      a1[r] += w * xv.y;
    }
  }

  if (mode == 0) {
    #pragma unroll
    for (int r = 0; r < 16; ++r) {
      float2 st = make_float2(a0[r] + bl[r], a1[r] + bl[r]);
      *(float2*)&outf[((size_t)b * C8_ + d0 + r) * N_ + n] = st;
    }
  } else {
    u32 p0[8], p1[8];
    #pragma unroll
    for (int r = 0; r < 8; ++r) {
      p0[r] = (u32)f2bf(a0[2*r] + bl[2*r]) | ((u32)f2bf(a0[2*r+1] + bl[2*r+1]) << 16);
      p1[r] = (u32)f2bf(a1[2*r] + bl[2*r]) | ((u32)f2bf(a1[2*r+1] + bl[2*r+1]) << 16);
    }
    u16* dst0 = vb + ((size_t)b * N_ + n) * C_ + d0;
    u16* dst1 = dst0 + C_;
    *(uint4*)(dst0)     = make_uint4(p0[0], p0[1], p0[2], p0[3]);
    *(uint4*)(dst0 + 8) = make_uint4(p0[4], p0[5], p0[6], p0[7]);
    *(uint4*)(dst1)     = make_uint4(p1[0], p1[1], p1[2], p1[3]);
    *(uint4*)(dst1 + 8) = make_uint4(p1[4], p1[5], p1[6], p1[7]);
  }
}

// ---------------------------------------------------------------------------
// Flash-style attention + residual.
//   energy[i,j] = sum_d q[i,d]*k[d,j]; attn = softmax_j; out[c,i] = sum_j v[c,j]*attn[i,j]
//   h[b,c,i] = out + x   -> f32 (B,C,N)
// grid (N/32, B), block 256.  TI=32 queries/block, TJ=64 keys/tile.
// ---------------------------------------------------------------------------
__global__ __launch_bounds__(256) void attn_kernel(
    const float* __restrict__ qb,   // (B,C8,N)
    const float* __restrict__ kb,   // (B,C8,N)
    const u16*  __restrict__ vb,    // (B,N,C) bf16
    const float* __restrict__ x,    // (B,C,N) f32
    float* __restrict__ hb)         // (B,C,N) f32
{
  constexpr int TI = 32, TJ = 64;
  __shared__ __align__(16) float qs[TI][36];     // [ti][d], stride 36 (16B-aligned rows)
  __shared__ __align__(16) u16   vs[TJ][C_];     // 32 KB, [jl][c]
  __shared__ __align__(16) float ps[TJ][TI];     // 8 KB, [jl][ti]
  __shared__ float red1[8][TI];
  __shared__ float red2[8][TI];
  __shared__ float m_s[TI], l_s[TI], al_s[TI];

  const int tid = threadIdx.x;
  const int b   = blockIdx.y;
  const int i0  = blockIdx.x * TI;

  // stage q tile (coalesced over ti), init softmax state
  for (int idx = tid; idx < TI * C8_; idx += 256) {
    int ti = idx & 31, d = idx >> 5;
    qs[ti][d] = qb[((size_t)b * C8_ + d) * N_ + i0 + ti];
  }
  if (tid < TI) { m_s[tid] = -1e30f; l_s[tid] = 0.f; }

  const int jl  = tid & 63;        // QK: key within tile
  const int tiq = tid >> 6;        // QK: query group (8 queries)
  const int cg  = tid & 63;        // PV: channel group
  const int c0  = cg * 4;
  const int tig = tid >> 6;        // PV: query group
  const int ti0 = tig * 8;
  const int sti = tid & 31;        // softmax: query
  const int prt = tid >> 5;        // softmax: partition 0..7

  float o[4][8];
  #pragma unroll
  for (int a = 0; a < 4; ++a)
    #pragma unroll
    for (int r = 0; r < 8; ++r) o[a][r] = 0.f;

  __syncthreads();

  const float* kp = kb + (size_t)b * C8_ * N_ + jl;

  for (int j0 = 0; j0 < N_; j0 += TJ) {
    __syncthreads();   // (1) previous PV done reading vs/ps

    // stage V tile: contiguous 32 KB copy
    {
      const uint4* src = (const uint4*)(vb + ((size_t)b * N_ + j0) * C_);
      uint4* dst = (uint4*)&vs[0][0];
      #pragma unroll
      for (int it = 0; it < 8; ++it) dst[tid + it * 256] = src[tid + it * 256];
    }

    // QK: scores for 8 queries at key j0+jl
    float s[8];
    #pragma unroll
    for (int r = 0; r < 8; ++r) s[r] = 0.f;
    #pragma unroll
    for (int d4 = 0; d4 < C8_; d4 += 4) {
      float k0 = kp[(size_t)(d4 + 0) * N_ + j0];
      float k1 = kp[(size_t)(d4 + 1) * N_ + j0];
      float k2 = kp[(size_t)(d4 + 2) * N_ + j0];
      float k3 = kp[(size_t)(d4 + 3) * N_ + j0];
      #pragma unroll
      for (int r = 0; r < 8; ++r) {
        float4 qv = *(const float4*)&qs[tiq * 8 + r][d4];
        s[r] += qv.x * k0 + qv.y * k1 + qv.z * k2 + qv.w * k3;
      }
    }
    #pragma unroll
    for (int r = 0; r < 8; ++r) ps[jl][tiq * 8 + r] = s[r];

    __syncthreads();   // (2) vs, ps ready

    // softmax phase A: partial max over this partition's 8 keys
    float pm = -1e30f;
    #pragma unroll
    for (int e = 0; e < 8; ++e) pm = fmaxf(pm, ps[prt * 8 + e][sti]);
    red1[prt][sti] = pm;

    __syncthreads();   // (3)

    // phase B: new max, alpha, exponentiate in place, partial sums
    float mold = m_s[sti];
    float mnew = mold;
    #pragma unroll
    for (int p = 0; p < 8; ++p) mnew = fmaxf(mnew, red1[p][sti]);
    float alpha = __expf(mold - mnew);
    float psum = 0.f;
    #pragma unroll
    for (int e = 0; e < 8; ++e) {
      float pv = __expf(ps[prt * 8 + e][sti] - mnew);
      ps[prt * 8 + e][sti] = pv;
      psum += pv;
    }
    red2[prt][sti] = psum;

    __syncthreads();   // (4)

    // phase C: one thread per query updates running state
    if (tid < TI) {
      float tot = 0.f;
      #pragma unroll
      for (int p = 0; p < 8; ++p) tot += red2[p][tid];
      l_s[tid]  = l_s[tid] * alpha + tot;
      m_s[tid]  = mnew;
      al_s[tid] = alpha;
    }

    __syncthreads();   // (5) state ready

    // PV: rescale and accumulate, 4 channels x 8 queries per thread
    float al[8];
    #pragma unroll
    for (int r = 0; r < 8; ++r) al[r] = al_s[ti0 + r];
    #pragma unroll
    for (int a = 0; a < 4; ++a)
      #pragma unroll
      for (int r = 0; r < 8; ++r) o[a][r] *= al[r];

    for (int j = 0; j < TJ; ++j) {
      float4 pA = *(const float4*)&ps[j][ti0];
      float4 pB = *(const float4*)&ps[j][ti0 + 4];
      uint2 vv  = *(const uint2*)&vs[j][c0];
      float vr[4] = { bflo(vv.x), bfhi(vv.x), bflo(vv.y), bfhi(vv.y) };
      float pr[8] = { pA.x, pA.y, pA.z, pA.w, pB.x, pB.y, pB.z, pB.w };
      #pragma unroll
      for (int a = 0; a < 4; ++a)
        #pragma unroll
        for (int r = 0; r < 8; ++r) o[a][r] += vr[a] * pr[r];
    }
  }

  // epilogue: divide by l, add residual, write h
  float invl[8];
  #pragma unroll
  for (int r = 0; r < 8; ++r) invl[r] = 1.f / l_s[ti0 + r];

  #pragma unroll
  for (int a = 0; a < 4; ++a) {
    int c = c0 + a;
    const float* xp = x + ((size_t)b * C_ + c) * N_ + i0 + ti0;
    float*       hp = hb + ((size_t)b * C_ + c) * N_ + i0 + ti0;
    float4 xA = *(const float4*)xp;
    float4 xB = *(const float4*)(xp + 4);
    float xr[8] = { xA.x, xA.y, xA.z, xA.w, xB.x, xB.y, xB.z, xB.w };
    float res[8];
    #pragma unroll
    for (int r = 0; r < 8; ++r) res[r] = o[a][r] * invl[r] + xr[r];
    *(float4*)hp       = make_float4(res[0], res[1], res[2], res[3]);
    *(float4*)(hp + 4) = make_float4(res[4], res[5], res[6], res[7]);
  }
}

// ---------------------------------------------------------------------------
// Final 1x1 conv: out[b,d,n] = sum_c h[b,c,n]*Wo[d,c] + bo[d]  -> f32 (B,C,N)
// grid (N/512, C/16, B), block 256.
// ---------------------------------------------------------------------------
__global__ __launch_bounds__(256) void out_proj(
    const float* __restrict__ hb,
    const float* __restrict__ Wo, const float* __restrict__ bo,
    float* __restrict__ out)
{
  __shared__ __align__(16) float wl[C_][16];
  __shared__ float bl[16];
  const int tid = threadIdx.x;
  const int b   = blockIdx.z;
  const int d0  = blockIdx.y * 16;

  for (int idx = tid; idx < C_ * 16; idx += 256) {
    int r = idx >> 8, c = idx & 255;
    wl[c][r] = Wo[(d0 + r) * C_ + c];
  }
  if (tid < 16) bl[tid] = bo[d0 + tid];
  __syncthreads();

  const int n = blockIdx.x * 512 + tid * 2;
  float a0[16], a1[16];
  #pragma unroll
  for (int r = 0; r < 16; ++r) { a0[r] = 0.f; a1[r] = 0.f; }

  const float* hp = hb + (size_t)b * C_ * N_ + n;
  for (int c = 0; c < C_; ++c) {
    float2 xv = *(const float2*)(hp + (size_t)c * N_);
    #pragma unroll
    for (int r = 0; r < 16; ++r) {
      float w = wl[c][r];
      a0[r] += w * xv.x;
      a1[r] += w * xv.y;
    }
  }

  #pragma unroll
  for (int r = 0; r < 16; ++r) {
    float2 st = make_float2(a0[r] + bl[r], a1[r] + bl[r]);
    *(float2*)&out[((size_t)b * C_ + d0 + r) * N_ + n] = st;
  }
}

// ---------------------------------------------------------------------------
extern "C" void kernel_launch(void* const* d_in, const int* in_sizes, int n_in,
                              void* d_out, int out_size, void* d_ws, size_t ws_size,
                              hipStream_t stream)
{
  const float* x  = (const float*)d_in[0];
  const float* Wq = (const float*)d_in[1];
  const float* bq = (const float*)d_in[2];
  const float* Wk = (const float*)d_in[3];
  const float* bk = (const float*)d_in[4];
  const float* Wv = (const float*)d_in[5];
  const float* bv = (const float*)d_in[6];
  const float* Wo = (const float*)d_in[7];
  const float* bo = (const float*)d_in[8];

  // workspace layout (28 MB total)
  float* qb = (float*)d_ws;                         // B*C8*N f32 = 2 MB
  float* kb = qb + (size_t)B_ * C8_ * N_;           // 2 MB
  u16*  vb  = (u16*)(kb + (size_t)B_ * C8_ * N_);   // B*N*C bf16 = 8 MB
  float* hb = (float*)(vb + (size_t)B_ * N_ * C_);  // B*C*N f32 = 16 MB

  float* out = (float*)d_out;

  qkv_proj<<<dim3(N_ / 512, 20, B_), 256, 0, stream>>>(
      x, Wq, bq, Wk, bk, Wv, bv, qb, kb, vb);
  attn_kernel<<<dim3(N_ / 32, B_), 256, 0, stream>>>(qb, kb, vb, x, hb);
  out_proj<<<dim3(N_ / 512, C_ / 16, B_), 256, 0, stream>>>(hb, Wo, bo, out);
}

// Round 3
// 567.274 us; speedup vs baseline: 1.3416x; 1.3416x over previous
//
#include <hip/hip_runtime.h>

#define DEV __device__ __forceinline__

constexpr int B_  = 4;
constexpr int C_  = 256;
constexpr int C8_ = 32;
constexpr int N_  = 4096;   // 64*64

using u16 = unsigned short;
using u32 = unsigned int;

typedef __attribute__((ext_vector_type(8))) short bf16x8;
typedef __attribute__((ext_vector_type(4))) float f32x4;

DEV float bf2f(u16 u) { return __uint_as_float(((u32)u) << 16); }
DEV u16   f2bf(float f) {
  u32 i = __float_as_uint(f);
  i += 0x7fffu + ((i >> 16) & 1u);   // round-to-nearest-even
  return (u16)(i >> 16);
}

// ---------------------------------------------------------------------------
// Fused q/k/v 1x1-conv projections (f32 inputs -> bf16 outputs).
//   qt[b,n,d] bf16 (B,N,32);  kt[b,n,d] bf16 (B,N,32);  vb[b,c,n] bf16 (B,C,N)
// grid (N/512, 20, B), block 256.  blockIdx.y: 0-1 q, 2-3 k, 4-19 v (16 d each)
// ---------------------------------------------------------------------------
__global__ __launch_bounds__(256) void qkv_proj(
    const float* __restrict__ x,
    const float* __restrict__ Wq, const float* __restrict__ bq,
    const float* __restrict__ Wk, const float* __restrict__ bk,
    const float* __restrict__ Wv, const float* __restrict__ bv,
    u16* __restrict__ qt, u16* __restrict__ kt, u16* __restrict__ vb)
{
  __shared__ __align__(16) float wl[C_][16];
  __shared__ float bl[16];
  const int tid = threadIdx.x;
  const int b   = blockIdx.z;
  const int yc  = blockIdx.y;

  const float *W, *bias;
  u16* outT = nullptr;   // (B,N,32) for q/k
  int d0, mode;
  if (yc < 2)      { W = Wq; bias = bq; d0 = yc * 16;       outT = qt; mode = 0; }
  else if (yc < 4) { W = Wk; bias = bk; d0 = (yc - 2) * 16; outT = kt; mode = 0; }
  else             { W = Wv; bias = bv; d0 = (yc - 4) * 16; mode = 1; }

  for (int idx = tid; idx < C_ * 16; idx += 256) {
    int r = idx >> 8, c = idx & 255;
    wl[c][r] = W[(d0 + r) * C_ + c];
  }
  if (tid < 16) bl[tid] = bias[d0 + tid];
  __syncthreads();

  const int n = blockIdx.x * 512 + tid * 2;
  float a0[16], a1[16];
  #pragma unroll
  for (int r = 0; r < 16; ++r) { a0[r] = 0.f; a1[r] = 0.f; }

  const float* xp = x + (size_t)b * C_ * N_ + n;
  for (int c = 0; c < C_; ++c) {
    float2 xv = *(const float2*)(xp + (size_t)c * N_);
    #pragma unroll
    for (int r = 0; r < 16; ++r) {
      float w = wl[c][r];
      a0[r] += w * xv.x;
      a1[r] += w * xv.y;
    }
  }

  if (mode == 0) {
    // q/k: write 16 bf16 per pixel at (B,N,32)[n][d0..d0+16]
    u32 p0[8], p1[8];
    #pragma unroll
    for (int r = 0; r < 8; ++r) {
      p0[r] = (u32)f2bf(a0[2*r] + bl[2*r]) | ((u32)f2bf(a0[2*r+1] + bl[2*r+1]) << 16);
      p1[r] = (u32)f2bf(a1[2*r] + bl[2*r]) | ((u32)f2bf(a1[2*r+1] + bl[2*r+1]) << 16);
    }
    u16* dst0 = outT + ((size_t)b * N_ + n) * C8_ + d0;
    u16* dst1 = dst0 + C8_;
    *(uint4*)(dst0)     = make_uint4(p0[0], p0[1], p0[2], p0[3]);
    *(uint4*)(dst0 + 8) = make_uint4(p0[4], p0[5], p0[6], p0[7]);
    *(uint4*)(dst1)     = make_uint4(p1[0], p1[1], p1[2], p1[3]);
    *(uint4*)(dst1 + 8) = make_uint4(p1[4], p1[5], p1[6], p1[7]);
  } else {
    // v: write (B,C,N) bf16, packed pairs over n -> coalesced
    #pragma unroll
    for (int r = 0; r < 16; ++r) {
      u32 pk = (u32)f2bf(a0[r] + bl[r]) | ((u32)f2bf(a1[r] + bl[r]) << 16);
      *(u32*)&vb[((size_t)b * C_ + d0 + r) * N_ + n] = pk;
    }
  }
}

// ---------------------------------------------------------------------------
// MFMA flash attention.  TI=64 queries/block (wave w owns rows 16w..16w+16),
// TJ=64 keys per tile, d=32 (one MFMA K-step).
//   S = Q K^T (16x16x32 MFMA), wave-private online softmax in registers,
//   P -> LDS (C/D -> A layout), O += P V^T (2 MFMAs per 16-channel group).
// Writes pre-residual attn output as bf16 (B,N,C).
// grid (N/64, B), block 256.
// ---------------------------------------------------------------------------
__global__ __launch_bounds__(256) void attn_mfma(
    const u16* __restrict__ qt,   // (B,N,32) bf16
    const u16* __restrict__ kt,   // (B,N,32) bf16
    const u16* __restrict__ vb,   // (B,C,N) bf16
    u16* __restrict__ hb)         // (B,N,C) bf16 out (no residual)
{
  __shared__ __align__(16) u16 qs[64][40];     // [i][d]   pad 40 -> 5 KB
  __shared__ __align__(16) u16 ks[64][40];     // [j][d]   5 KB
  __shared__ __align__(16) u16 vs[C_][72];     // [c][j]   pad 72 -> 36 KB
  __shared__ __align__(16) u16 ps[4][16][72];  // per wave: [i][j] 9 KB

  const int tid  = threadIdx.x;
  const int lane = tid & 63;
  const int w    = tid >> 6;
  const int m    = lane & 15;
  const int quad = lane >> 4;
  const int b    = blockIdx.y;
  const int i0   = blockIdx.x * 64;

  // stage Q tile: 64 rows x 32 bf16 = 256 x uint4, one per thread
  {
    int row = tid >> 2, xq = tid & 3;
    uint4 v = *(const uint4*)(qt + ((size_t)b * N_ + i0 + row) * C8_ + xq * 8);
    *(uint4*)&qs[row][xq * 8] = v;
  }
  __syncthreads();

  // fixed A-fragment: Q rows w*16..w*16+16, A[m=lane&15][k=quad*8+j]
  const bf16x8 qfrag = *(const bf16x8*)&qs[w * 16 + m][quad * 8];

  f32x4 o[16];
  #pragma unroll
  for (int ct = 0; ct < 16; ++ct) o[ct] = (f32x4){0.f, 0.f, 0.f, 0.f};
  float m_r[4] = {-1e30f, -1e30f, -1e30f, -1e30f};
  float l_r[4] = {0.f, 0.f, 0.f, 0.f};

  for (int j0 = 0; j0 < N_; j0 += 64) {
    __syncthreads();   // all waves done reading ks/vs of previous tile

    // stage K tile: 64 x 32 bf16, one uint4 per thread
    {
      int row = tid >> 2, xq = tid & 3;
      uint4 v = *(const uint4*)(kt + ((size_t)b * N_ + j0 + row) * C8_ + xq * 8);
      *(uint4*)&ks[row][xq * 8] = v;
    }
    // stage V tile: 256 c x 64 j bf16 = 2048 uint4, 8 per thread
    #pragma unroll
    for (int it = 0; it < 8; ++it) {
      int chunk = tid + it * 256;
      int c = chunk >> 3, xq = chunk & 7;
      uint4 v = *(const uint4*)(vb + ((size_t)b * C_ + c) * N_ + j0 + xq * 8);
      *(uint4*)&vs[c][xq * 8] = v;
    }
    __syncthreads();

    // QK^T: S[16 rows][64 cols] in 4 MFMAs
    f32x4 s[4];
    #pragma unroll
    for (int t = 0; t < 4; ++t) {
      bf16x8 kf = *(const bf16x8*)&ks[t * 16 + m][quad * 8];
      s[t] = __builtin_amdgcn_mfma_f32_16x16x32_bf16(
          qfrag, kf, (f32x4){0.f, 0.f, 0.f, 0.f}, 0, 0, 0);
    }

    // online softmax (wave-private; row i = quad*4+r lives in this quad)
    float mx[4], al[4], sm[4];
    #pragma unroll
    for (int r = 0; r < 4; ++r)
      mx[r] = fmaxf(fmaxf(s[0][r], s[1][r]), fmaxf(s[2][r], s[3][r]));
    #pragma unroll
    for (int mk = 1; mk <= 8; mk <<= 1)
      #pragma unroll
      for (int r = 0; r < 4; ++r)
        mx[r] = fmaxf(mx[r], __shfl_xor(mx[r], mk));
    #pragma unroll
    for (int r = 0; r < 4; ++r) {
      float mn = fmaxf(m_r[r], mx[r]);
      al[r] = __expf(m_r[r] - mn);
      m_r[r] = mn;
    }
    float p[4][4];
    #pragma unroll
    for (int r = 0; r < 4; ++r) sm[r] = 0.f;
    #pragma unroll
    for (int t = 0; t < 4; ++t)
      #pragma unroll
      for (int r = 0; r < 4; ++r) {
        p[t][r] = __expf(s[t][r] - m_r[r]);
        sm[r] += p[t][r];
      }
    #pragma unroll
    for (int mk = 1; mk <= 8; mk <<= 1)
      #pragma unroll
      for (int r = 0; r < 4; ++r)
        sm[r] += __shfl_xor(sm[r], mk);
    #pragma unroll
    for (int r = 0; r < 4; ++r) l_r[r] = l_r[r] * al[r] + sm[r];

    // P: C/D layout -> LDS [i][j] (wave-private, DS ops wave-ordered)
    #pragma unroll
    for (int t = 0; t < 4; ++t)
      #pragma unroll
      for (int r = 0; r < 4; ++r)
        ps[w][quad * 4 + r][t * 16 + m] = f2bf(p[t][r]);

    // A-fragments of P (rows m, k = jl)
    bf16x8 pf0 = *(const bf16x8*)&ps[w][m][quad * 8];
    bf16x8 pf1 = *(const bf16x8*)&ps[w][m][32 + quad * 8];

    // rescale O by alpha (O rows in C/D layout match alpha indexing)
    #pragma unroll
    for (int ct = 0; ct < 16; ++ct)
      #pragma unroll
      for (int r = 0; r < 4; ++r) o[ct][r] *= al[r];

    // PV: O[16 x 256] += P[16 x 64] * V^T[64 x 256]
    #pragma unroll
    for (int ct = 0; ct < 16; ++ct) {
      bf16x8 vf0 = *(const bf16x8*)&vs[ct * 16 + m][quad * 8];
      bf16x8 vf1 = *(const bf16x8*)&vs[ct * 16 + m][32 + quad * 8];
      o[ct] = __builtin_amdgcn_mfma_f32_16x16x32_bf16(pf0, vf0, o[ct], 0, 0, 0);
      o[ct] = __builtin_amdgcn_mfma_f32_16x16x32_bf16(pf1, vf1, o[ct], 0, 0, 0);
    }
  }

  // epilogue: O /= l, write bf16 (B,N,C)
  float inv[4];
  #pragma unroll
  for (int r = 0; r < 4; ++r) inv[r] = 1.f / l_r[r];

  #pragma unroll
  for (int ct = 0; ct < 16; ++ct)
    #pragma unroll
    for (int r = 0; r < 4; ++r) {
      size_t row = (size_t)b * N_ + i0 + w * 16 + quad * 4 + r;
      hb[row * C_ + ct * 16 + m] = f2bf(o[ct][r] * inv[r]);
    }
}

// ---------------------------------------------------------------------------
// Final 1x1 conv with fused residual:
//   out[b,d,n] = sum_c Wo[d,c]*(hb[b,n,c] + x[b,c,n]) + bo[d]   -> f32 (B,C,N)
// grid (N/512, C/16, B), block 256.
// ---------------------------------------------------------------------------
__global__ __launch_bounds__(256) void out_proj(
    const u16* __restrict__ hb,    // (B,N,C) bf16
    const float* __restrict__ x,   // (B,C,N) f32
    const float* __restrict__ Wo, const float* __restrict__ bo,
    float* __restrict__ out)
{
  __shared__ __align__(16) float wl[C_][16];
  __shared__ float bl[16];
  const int tid = threadIdx.x;
  const int b   = blockIdx.z;
  const int d0  = blockIdx.y * 16;

  for (int idx = tid; idx < C_ * 16; idx += 256) {
    int r = idx >> 8, c = idx & 255;
    wl[c][r] = Wo[(d0 + r) * C_ + c];
  }
  if (tid < 16) bl[tid] = bo[d0 + tid];
  __syncthreads();

  const int n = blockIdx.x * 512 + tid * 2;
  float a0[16], a1[16];
  #pragma unroll
  for (int r = 0; r < 16; ++r) { a0[r] = 0.f; a1[r] = 0.f; }

  const u16* hp0 = hb + ((size_t)b * N_ + n) * C_;
  const u16* hp1 = hp0 + C_;
  const float* xp = x + (size_t)b * C_ * N_ + n;
  for (int c = 0; c < C_; ++c) {
    float2 xv = *(const float2*)(xp + (size_t)c * N_);
    float s0 = bf2f(hp0[c]) + xv.x;
    float s1 = bf2f(hp1[c]) + xv.y;
    #pragma unroll
    for (int r = 0; r < 16; ++r) {
      float w = wl[c][r];
      a0[r] += w * s0;
      a1[r] += w * s1;
    }
  }

  #pragma unroll
  for (int r = 0; r < 16; ++r) {
    float2 st = make_float2(a0[r] + bl[r], a1[r] + bl[r]);
    *(float2*)&out[((size_t)b * C_ + d0 + r) * N_ + n] = st;
  }
}

// ---------------------------------------------------------------------------
extern "C" void kernel_launch(void* const* d_in, const int* in_sizes, int n_in,
                              void* d_out, int out_size, void* d_ws, size_t ws_size,
                              hipStream_t stream)
{
  const float* x  = (const float*)d_in[0];
  const float* Wq = (const float*)d_in[1];
  const float* bq = (const float*)d_in[2];
  const float* Wk = (const float*)d_in[3];
  const float* bk = (const float*)d_in[4];
  const float* Wv = (const float*)d_in[5];
  const float* bv = (const float*)d_in[6];
  const float* Wo = (const float*)d_in[7];
  const float* bo = (const float*)d_in[8];

  // workspace layout (18 MB total)
  u16* qt = (u16*)d_ws;                          // B*N*32 bf16 = 1 MB
  u16* kt = qt + (size_t)B_ * N_ * C8_;          // 1 MB
  u16* vb = kt + (size_t)B_ * N_ * C8_;          // B*C*N bf16 = 8 MB
  u16* hb = vb + (size_t)B_ * C_ * N_;           // B*N*C bf16 = 8 MB

  float* out = (float*)d_out;

  qkv_proj<<<dim3(N_ / 512, 20, B_), 256, 0, stream>>>(
      x, Wq, bq, Wk, bk, Wv, bv, qt, kt, vb);
  attn_mfma<<<dim3(N_ / 64, B_), 256, 0, stream>>>(qt, kt, vb, hb);
  out_proj<<<dim3(N_ / 512, C_ / 16, B_), 256, 0, stream>>>(hb, x, Wo, bo, out);
}

// Round 4
// 296.782 us; speedup vs baseline: 2.5643x; 1.9114x over previous
//
#include <hip/hip_runtime.h>

#define DEV __device__ __forceinline__

constexpr int B_  = 4;
constexpr int C_  = 256;
constexpr int C8_ = 32;
constexpr int N_  = 4096;   // 64*64

using u16 = unsigned short;
using u32 = unsigned int;

typedef __attribute__((ext_vector_type(8))) short bf16x8;
typedef __attribute__((ext_vector_type(4))) float f32x4;

DEV float bflo(u32 u) { return __uint_as_float(u << 16); }
DEV float bfhi(u32 u) { return __uint_as_float(u & 0xffff0000u); }
DEV u16   f2bf(float f) {
  u32 i = __float_as_uint(f);
  i += 0x7fffu + ((i >> 16) & 1u);   // round-to-nearest-even
  return (u16)(i >> 16);
}

// ---------------------------------------------------------------------------
// Fused q/k/v 1x1-conv projections (f32 inputs -> bf16 outputs).
//   qt[b,n,d] bf16 (B,N,32);  kt[b,n,d] bf16 (B,N,32);  vb[b,c,n] bf16 (B,C,N)
// grid (N/512, 20, B), block 256.
// ---------------------------------------------------------------------------
__global__ __launch_bounds__(256) void qkv_proj(
    const float* __restrict__ x,
    const float* __restrict__ Wq, const float* __restrict__ bq,
    const float* __restrict__ Wk, const float* __restrict__ bk,
    const float* __restrict__ Wv, const float* __restrict__ bv,
    u16* __restrict__ qt, u16* __restrict__ kt, u16* __restrict__ vb)
{
  __shared__ __align__(16) float wl[C_][16];
  __shared__ float bl[16];
  const int tid = threadIdx.x;
  const int b   = blockIdx.z;
  const int yc  = blockIdx.y;

  const float *W, *bias;
  u16* outT = nullptr;
  int d0, mode;
  if (yc < 2)      { W = Wq; bias = bq; d0 = yc * 16;       outT = qt; mode = 0; }
  else if (yc < 4) { W = Wk; bias = bk; d0 = (yc - 2) * 16; outT = kt; mode = 0; }
  else             { W = Wv; bias = bv; d0 = (yc - 4) * 16; mode = 1; }

  for (int idx = tid; idx < C_ * 16; idx += 256) {
    int r = idx >> 8, c = idx & 255;
    wl[c][r] = W[(d0 + r) * C_ + c];
  }
  if (tid < 16) bl[tid] = bias[d0 + tid];
  __syncthreads();

  const int n = blockIdx.x * 512 + tid * 2;
  float a0[16], a1[16];
  #pragma unroll
  for (int r = 0; r < 16; ++r) { a0[r] = 0.f; a1[r] = 0.f; }

  const float* xp = x + (size_t)b * C_ * N_ + n;
  for (int c = 0; c < C_; ++c) {
    float2 xv = *(const float2*)(xp + (size_t)c * N_);
    #pragma unroll
    for (int r = 0; r < 16; ++r) {
      float w = wl[c][r];
      a0[r] += w * xv.x;
      a1[r] += w * xv.y;
    }
  }

  if (mode == 0) {
    u32 p0[8], p1[8];
    #pragma unroll
    for (int r = 0; r < 8; ++r) {
      p0[r] = (u32)f2bf(a0[2*r] + bl[2*r]) | ((u32)f2bf(a0[2*r+1] + bl[2*r+1]) << 16);
      p1[r] = (u32)f2bf(a1[2*r] + bl[2*r]) | ((u32)f2bf(a1[2*r+1] + bl[2*r+1]) << 16);
    }
    u16* dst0 = outT + ((size_t)b * N_ + n) * C8_ + d0;
    u16* dst1 = dst0 + C8_;
    *(uint4*)(dst0)     = make_uint4(p0[0], p0[1], p0[2], p0[3]);
    *(uint4*)(dst0 + 8) = make_uint4(p0[4], p0[5], p0[6], p0[7]);
    *(uint4*)(dst1)     = make_uint4(p1[0], p1[1], p1[2], p1[3]);
    *(uint4*)(dst1 + 8) = make_uint4(p1[4], p1[5], p1[6], p1[7]);
  } else {
    #pragma unroll
    for (int r = 0; r < 16; ++r) {
      u32 pk = (u32)f2bf(a0[r] + bl[r]) | ((u32)f2bf(a1[r] + bl[r]) << 16);
      *(u32*)&vb[((size_t)b * C_ + d0 + r) * N_ + n] = pk;
    }
  }
}

// ---------------------------------------------------------------------------
// MFMA flash attention, split-K=2.
//   S^T = K Q^T (lane&15 = query -> register softmax), P via LDS (dbuf),
//   PV channel-split across waves, K/V fragments direct from global.
// Writes unnormalized O (f32) + m,l per (slice, b, n).
// grid (N/64, 2, B) linearized+swizzled; block 256 (4 waves).
// ---------------------------------------------------------------------------
__global__ __launch_bounds__(256) void attn_mfma(
    const u16* __restrict__ qt,   // (B,N,32) bf16
    const u16* __restrict__ kt,   // (B,N,32) bf16
    const u16* __restrict__ vb,   // (B,C,N) bf16
    float* __restrict__ Opart,    // (2,B,N,C) f32 unnormalized
    float* __restrict__ ml)       // [0:2*B*N) m, [2*B*N:4*B*N) l
{
  __shared__ __align__(16) u16  ps[2][64][72];   // P dbuf, [q][j] pad72 -> 18 KB
  __shared__ __align__(16) float als[2][64];

  const int tid  = threadIdx.x;
  const int lane = tid & 63;
  const int w    = tid >> 6;
  const int m    = lane & 15;
  const int quad = lane >> 4;

  // XCD-locality swizzle: group (b,ksl) per XCD (heuristic, speed-only)
  const int lid = blockIdx.x + gridDim.x * (blockIdx.y + gridDim.y * blockIdx.z);
  const int grp = lid & 7;
  const int ksl = grp & 1;
  const int b   = grp >> 1;
  const int i0  = (lid >> 3) * 64;

  // Q B-fragment: row = query i0 + w*16 + m, k = quad*8.. (fixed all loop)
  const bf16x8 qfrag =
      *(const bf16x8*)(qt + ((size_t)b * N_ + i0 + w * 16 + m) * C8_ + quad * 8);

  const u16* kbase = kt + (size_t)b * N_ * C8_;
  const u16* vrow  = vb + ((size_t)b * C_ + w * 64 + m) * N_;  // +ct*16*N per ct

  f32x4 o[4][4];
  #pragma unroll
  for (int t = 0; t < 4; ++t)
    #pragma unroll
    for (int ct = 0; ct < 4; ++ct) o[t][ct] = (f32x4){0.f, 0.f, 0.f, 0.f};
  float m_r = -1e30f, l_r = 0.f;

  const int jbeg = ksl * 2048, jend = jbeg + 2048;
  int buf = 0;

  for (int j0 = jbeg; j0 < jend; j0 += 64, buf ^= 1) {
    // K A-fragments: row j = j0 + t*16 + m, cols quad*8..
    bf16x8 kA[4];
    #pragma unroll
    for (int t = 0; t < 4; ++t)
      kA[t] = *(const bf16x8*)(kbase + (size_t)(j0 + t * 16 + m) * C8_ + quad * 8);
    // V B-fragments: row c = w*64 + ct*16 + m, cols j0 + h*32 + quad*8
    bf16x8 vB[4][2];
    #pragma unroll
    for (int ct = 0; ct < 4; ++ct)
      #pragma unroll
      for (int h = 0; h < 2; ++h)
        vB[ct][h] = *(const bf16x8*)(vrow + (size_t)ct * 16 * N_ + j0 + h * 32 + quad * 8);

    // S^T[j][q]: A=K rows j, B=Q rows q.  D: row(j_rel)=quad*4+r, col(q)=m
    f32x4 s[4];
    #pragma unroll
    for (int t = 0; t < 4; ++t)
      s[t] = __builtin_amdgcn_mfma_f32_16x16x32_bf16(
          kA[t], qfrag, (f32x4){0.f, 0.f, 0.f, 0.f}, 0, 0, 0);

    // register softmax: lane owns query q = w*16+m, its 16 j-values in regs
    float mx = -1e30f;
    #pragma unroll
    for (int t = 0; t < 4; ++t)
      #pragma unroll
      for (int r = 0; r < 4; ++r) mx = fmaxf(mx, s[t][r]);
    mx = fmaxf(mx, __shfl_xor(mx, 16));
    mx = fmaxf(mx, __shfl_xor(mx, 32));
    float mn = fmaxf(m_r, mx);
    float al = __expf(m_r - mn);
    m_r = mn;
    float p[4][4], sm = 0.f;
    #pragma unroll
    for (int t = 0; t < 4; ++t)
      #pragma unroll
      for (int r = 0; r < 4; ++r) {
        p[t][r] = __expf(s[t][r] - mn);
        sm += p[t][r];
      }
    sm += __shfl_xor(sm, 16);
    sm += __shfl_xor(sm, 32);
    l_r = l_r * al + sm;

    // write P (packed b64: 4 consecutive j) and alpha
    #pragma unroll
    for (int t = 0; t < 4; ++t) {
      u32 lo = (u32)f2bf(p[t][0]) | ((u32)f2bf(p[t][1]) << 16);
      u32 hi = (u32)f2bf(p[t][2]) | ((u32)f2bf(p[t][3]) << 16);
      *(uint2*)&ps[buf][w * 16 + m][t * 16 + quad * 4] = make_uint2(lo, hi);
    }
    if (quad == 0) als[buf][w * 16 + m] = al;

    __syncthreads();   // P/alpha of this tile visible to all waves

    // rescale O by alphas (rows of D = queries t*16 + quad*4 + r)
    #pragma unroll
    for (int t = 0; t < 4; ++t) {
      float4 alv = *(const float4*)&als[buf][t * 16 + quad * 4];
      #pragma unroll
      for (int ct = 0; ct < 4; ++ct) {
        o[t][ct][0] *= alv.x; o[t][ct][1] *= alv.y;
        o[t][ct][2] *= alv.z; o[t][ct][3] *= alv.w;
      }
    }

    // PV: A = P rows (t*16+m), B = V rows c
    #pragma unroll
    for (int t = 0; t < 4; ++t) {
      bf16x8 pf0 = *(const bf16x8*)&ps[buf][t * 16 + m][quad * 8];
      bf16x8 pf1 = *(const bf16x8*)&ps[buf][t * 16 + m][32 + quad * 8];
      #pragma unroll
      for (int ct = 0; ct < 4; ++ct) {
        o[t][ct] = __builtin_amdgcn_mfma_f32_16x16x32_bf16(pf0, vB[ct][0], o[t][ct], 0, 0, 0);
        o[t][ct] = __builtin_amdgcn_mfma_f32_16x16x32_bf16(pf1, vB[ct][1], o[t][ct], 0, 0, 0);
      }
    }
    // no trailing barrier: next iter writes the other P buffer
  }

  // epilogue: store unnormalized O + (m,l)
  float* Ob = Opart + (size_t)ksl * B_ * N_ * C_ + ((size_t)b * N_ + i0) * C_ + w * 64;
  #pragma unroll
  for (int t = 0; t < 4; ++t)
    #pragma unroll
    for (int ct = 0; ct < 4; ++ct)
      #pragma unroll
      for (int r = 0; r < 4; ++r)
        Ob[(size_t)(t * 16 + quad * 4 + r) * C_ + ct * 16 + m] = o[t][ct][r];

  if (quad == 0) {
    size_t mli = ((size_t)ksl * B_ + b) * N_ + i0 + w * 16 + m;
    ml[mli] = m_r;
    ml[(size_t)2 * B_ * N_ + mli] = l_r;
  }
}

// ---------------------------------------------------------------------------
// Split-K combine + transpose: hb[b,c,n] = (O0*w0 + O1*w1)/l  -> bf16 (B,C,N)
// grid (N/64, B), block 256.
// ---------------------------------------------------------------------------
__global__ __launch_bounds__(256) void combine(
    const float* __restrict__ Opart, const float* __restrict__ ml,
    u16* __restrict__ hb)
{
  __shared__ __align__(16) u16 tile[256][72];   // [c][n] pad72 -> 36 KB
  const int tid = threadIdx.x;
  const int b   = blockIdx.y;
  const int n0  = blockIdx.x * 64;
  const int nl  = tid & 63;
  const int cg  = tid >> 6;

  size_t base = (size_t)b * N_ + n0 + nl;
  float m0 = ml[base];
  float m1 = ml[(size_t)B_ * N_ + base];
  float l0 = ml[(size_t)2 * B_ * N_ + base];
  float l1 = ml[(size_t)3 * B_ * N_ + base];
  float M  = fmaxf(m0, m1);
  float w0 = __expf(m0 - M), w1 = __expf(m1 - M);
  float inv = 1.f / (l0 * w0 + l1 * w1);
  w0 *= inv; w1 *= inv;

  const float* O0 = Opart + base * C_ + cg * 64;
  const float* O1 = O0 + (size_t)B_ * N_ * C_;
  #pragma unroll
  for (int cc = 0; cc < 64; cc += 4) {
    float4 a = *(const float4*)(O0 + cc);
    float4 c2 = *(const float4*)(O1 + cc);
    tile[cg * 64 + cc + 0][nl] = f2bf(a.x * w0 + c2.x * w1);
    tile[cg * 64 + cc + 1][nl] = f2bf(a.y * w0 + c2.y * w1);
    tile[cg * 64 + cc + 2][nl] = f2bf(a.z * w0 + c2.z * w1);
    tile[cg * 64 + cc + 3][nl] = f2bf(a.w * w0 + c2.w * w1);
  }
  __syncthreads();

  u16* dst = hb + ((size_t)b * C_ + tid) * N_ + n0;
  #pragma unroll
  for (int k2 = 0; k2 < 8; ++k2)
    ((uint4*)dst)[k2] = *(const uint4*)&tile[tid][k2 * 8];
}

// ---------------------------------------------------------------------------
// Final 1x1 conv with fused residual (h in (B,C,N) bf16, coalesced):
//   out[b,d,n] = sum_c Wo[d,c]*(h[b,c,n] + x[b,c,n]) + bo[d]   -> f32 (B,C,N)
// grid (N/512, C/16, B), block 256.
// ---------------------------------------------------------------------------
__global__ __launch_bounds__(256) void out_proj(
    const u16* __restrict__ hb,
    const float* __restrict__ x,
    const float* __restrict__ Wo, const float* __restrict__ bo,
    float* __restrict__ out)
{
  __shared__ __align__(16) float wl[C_][16];
  __shared__ float bl[16];
  const int tid = threadIdx.x;
  const int b   = blockIdx.z;
  const int d0  = blockIdx.y * 16;

  for (int idx = tid; idx < C_ * 16; idx += 256) {
    int r = idx >> 8, c = idx & 255;
    wl[c][r] = Wo[(d0 + r) * C_ + c];
  }
  if (tid < 16) bl[tid] = bo[d0 + tid];
  __syncthreads();

  const int n = blockIdx.x * 512 + tid * 2;
  float a0[16], a1[16];
  #pragma unroll
  for (int r = 0; r < 16; ++r) { a0[r] = 0.f; a1[r] = 0.f; }

  const u16*   hp = hb + (size_t)b * C_ * N_ + n;
  const float* xp = x  + (size_t)b * C_ * N_ + n;
  for (int c = 0; c < C_; ++c) {
    u32 hv = *(const u32*)(hp + (size_t)c * N_);
    float2 xv = *(const float2*)(xp + (size_t)c * N_);
    float s0 = bflo(hv) + xv.x;
    float s1 = bfhi(hv) + xv.y;
    #pragma unroll
    for (int r = 0; r < 16; ++r) {
      float w = wl[c][r];
      a0[r] += w * s0;
      a1[r] += w * s1;
    }
  }

  #pragma unroll
  for (int r = 0; r < 16; ++r) {
    float2 st = make_float2(a0[r] + bl[r], a1[r] + bl[r]);
    *(float2*)&out[((size_t)b * C_ + d0 + r) * N_ + n] = st;
  }
}

// ---------------------------------------------------------------------------
extern "C" void kernel_launch(void* const* d_in, const int* in_sizes, int n_in,
                              void* d_out, int out_size, void* d_ws, size_t ws_size,
                              hipStream_t stream)
{
  const float* x  = (const float*)d_in[0];
  const float* Wq = (const float*)d_in[1];
  const float* bq = (const float*)d_in[2];
  const float* Wk = (const float*)d_in[3];
  const float* bk = (const float*)d_in[4];
  const float* Wv = (const float*)d_in[5];
  const float* bv = (const float*)d_in[6];
  const float* Wo = (const float*)d_in[7];
  const float* bo = (const float*)d_in[8];

  // workspace layout (~50.3 MB)
  u16* qt = (u16*)d_ws;                               // B*N*32 bf16 = 1 MB
  u16* kt = qt + (size_t)B_ * N_ * C8_;               // 1 MB
  u16* vb = kt + (size_t)B_ * N_ * C8_;               // B*C*N bf16 = 8 MB
  u16* hb = vb + (size_t)B_ * C_ * N_;                // B*C*N bf16 = 8 MB
  float* Opart = (float*)(hb + (size_t)B_ * C_ * N_); // 2*B*N*C f32 = 32 MB
  float* ml = Opart + (size_t)2 * B_ * N_ * C_;       // 4*B*N f32 = 256 KB

  float* out = (float*)d_out;

  qkv_proj<<<dim3(N_ / 512, 20, B_), 256, 0, stream>>>(
      x, Wq, bq, Wk, bk, Wv, bv, qt, kt, vb);
  attn_mfma<<<dim3(N_ / 64, 2, B_), 256, 0, stream>>>(qt, kt, vb, Opart, ml);
  combine<<<dim3(N_ / 64, B_), 256, 0, stream>>>(Opart, ml, hb);
  out_proj<<<dim3(N_ / 512, C_ / 16, B_), 256, 0, stream>>>(hb, x, Wo, bo, out);
}

// Round 5
// 228.686 us; speedup vs baseline: 3.3278x; 1.2978x over previous
//
#include <hip/hip_runtime.h>

#define DEV __device__ __forceinline__

constexpr int B_  = 4;
constexpr int C_  = 256;
constexpr int C8_ = 32;
constexpr int N_  = 4096;   // 64*64

using u16 = unsigned short;
using u32 = unsigned int;

typedef __attribute__((ext_vector_type(8))) short bf16x8;
typedef __attribute__((ext_vector_type(4))) float f32x4;

DEV float bf2f(u16 u) { return __uint_as_float(((u32)u) << 16); }
DEV u16   f2bf(float f) {
  u32 i = __float_as_uint(f);
  i += 0x7fffu + ((i >> 16) & 1u);   // round-to-nearest-even
  return (u16)(i >> 16);
}

// build hi/lo bf16x8 fragments from 8 consecutive f32
DEV void cvt8(const float* p, bf16x8& hi, bf16x8& lo) {
  float4 a = *(const float4*)p;
  float4 b = *(const float4*)(p + 4);
  float f[8] = {a.x, a.y, a.z, a.w, b.x, b.y, b.z, b.w};
  #pragma unroll
  for (int j = 0; j < 8; ++j) {
    u16 h = f2bf(f[j]);
    hi[j] = (short)h;
    lo[j] = (short)f2bf(f[j] - bf2f(h));
  }
}

// ---------------------------------------------------------------------------
// Fused q/k/v 1x1-conv projections as MFMA GEMM (hi/lo split for accuracy).
//   qt,kt: (B,N,32) bf16;  vb: (B,C,N) bf16;  xT: (B,N,C) bf16 (for out_proj)
// grid (N/64, B), block 256 (4 waves).
//   wave w: v-channels [64w,64w+64) for all 64 n;  qk-tile w (16 d x 64 n).
// ---------------------------------------------------------------------------
__global__ __launch_bounds__(256) void qkv_mfma(
    const float* __restrict__ x,
    const float* __restrict__ Wq, const float* __restrict__ bq,
    const float* __restrict__ Wk, const float* __restrict__ bk,
    const float* __restrict__ Wv, const float* __restrict__ bv,
    u16* __restrict__ qt, u16* __restrict__ kt, u16* __restrict__ vb,
    u16* __restrict__ xT)
{
  __shared__ __align__(16) u16 xh[64][264];   // x^T hi, pad 264 -> 33 KB
  __shared__ __align__(16) u16 xl[64][264];   // x^T lo

  const int tid  = threadIdx.x;
  const int lane = tid & 63;
  const int w    = tid >> 6;
  const int m    = lane & 15;
  const int quad = lane >> 4;
  const int b    = blockIdx.y;
  const int n0   = blockIdx.x * 64;

  // stage x tile (256 c x 64 n), transposed, hi/lo split
  {
    const int nl = tid & 63, cb = tid >> 6;
    #pragma unroll 4
    for (int cc = 0; cc < 64; ++cc) {
      int c = cb + cc * 4;
      float v = x[((size_t)b * C_ + c) * N_ + n0 + nl];
      u16 h = f2bf(v);
      xh[nl][c] = h;
      xl[nl][c] = f2bf(v - bf2f(h));
    }
  }
  __syncthreads();

  // dump xT (hi) coalesced
  #pragma unroll
  for (int it = 0; it < 8; ++it) {
    int idx = tid + it * 256;
    int n = idx >> 5, q = idx & 31;
    *(uint4*)&xT[((size_t)b * N_ + n0 + n) * C_ + q * 8] = *(const uint4*)&xh[n][q * 8];
  }

  f32x4 ov[4][4];   // v accums [dt][nt]
  f32x4 oq[4];      // qk accums [nt]
  #pragma unroll
  for (int dt = 0; dt < 4; ++dt)
    #pragma unroll
    for (int nt = 0; nt < 4; ++nt) ov[dt][nt] = (f32x4){0.f, 0.f, 0.f, 0.f};
  #pragma unroll
  for (int nt = 0; nt < 4; ++nt) oq[nt] = (f32x4){0.f, 0.f, 0.f, 0.f};

  const float* Wqk = (w < 2) ? (Wq + (size_t)(w * 16) * C_)
                             : (Wk + (size_t)((w - 2) * 16) * C_);

  for (int K = 0; K < 8; ++K) {
    // x fragments (per n-tile); serve as B (v-part) and A (qk-part)
    bf16x8 xfh[4], xfl[4];
    #pragma unroll
    for (int nt = 0; nt < 4; ++nt) {
      xfh[nt] = *(const bf16x8*)&xh[nt * 16 + m][K * 32 + quad * 8];
      xfl[nt] = *(const bf16x8*)&xl[nt * 16 + m][K * 32 + quad * 8];
    }
    // v-part: A = Wv rows oc = 64w + dt*16 + m
    #pragma unroll
    for (int dt = 0; dt < 4; ++dt) {
      bf16x8 whi, wlo;
      cvt8(Wv + (size_t)(64 * w + dt * 16 + m) * C_ + K * 32 + quad * 8, whi, wlo);
      #pragma unroll
      for (int nt = 0; nt < 4; ++nt) {
        ov[dt][nt] = __builtin_amdgcn_mfma_f32_16x16x32_bf16(whi, xfh[nt], ov[dt][nt], 0, 0, 0);
        ov[dt][nt] = __builtin_amdgcn_mfma_f32_16x16x32_bf16(whi, xfl[nt], ov[dt][nt], 0, 0, 0);
        ov[dt][nt] = __builtin_amdgcn_mfma_f32_16x16x32_bf16(wlo, xfh[nt], ov[dt][nt], 0, 0, 0);
      }
    }
    // qk-part: B = Wqk row m (col index = d)
    {
      bf16x8 bhi, blo;
      cvt8(Wqk + (size_t)m * C_ + K * 32 + quad * 8, bhi, blo);
      #pragma unroll
      for (int nt = 0; nt < 4; ++nt) {
        oq[nt] = __builtin_amdgcn_mfma_f32_16x16x32_bf16(xfh[nt], bhi, oq[nt], 0, 0, 0);
        oq[nt] = __builtin_amdgcn_mfma_f32_16x16x32_bf16(xfl[nt], bhi, oq[nt], 0, 0, 0);
        oq[nt] = __builtin_amdgcn_mfma_f32_16x16x32_bf16(xfh[nt], blo, oq[nt], 0, 0, 0);
      }
    }
  }

  // v epilogue: D rows = oc, cols = n
  #pragma unroll
  for (int dt = 0; dt < 4; ++dt) {
    #pragma unroll
    for (int r = 0; r < 4; ++r) {
      int oc = 64 * w + dt * 16 + quad * 4 + r;
      float bias = bv[oc];
      #pragma unroll
      for (int nt = 0; nt < 4; ++nt)
        vb[((size_t)b * C_ + oc) * N_ + n0 + nt * 16 + m] = f2bf(ov[dt][nt][r] + bias);
    }
  }
  // qk epilogue: D rows = n, cols = d
  {
    u16* qk_out = (w < 2) ? qt : kt;
    const float* qk_bias = (w < 2) ? bq : bk;
    int dbase = (w & 1) * 16;
    float bias = qk_bias[dbase + m];
    #pragma unroll
    for (int nt = 0; nt < 4; ++nt)
      #pragma unroll
      for (int r = 0; r < 4; ++r)
        qk_out[((size_t)b * N_ + n0 + nt * 16 + quad * 4 + r) * C8_ + dbase + m] =
            f2bf(oq[nt][r] + bias);
  }
}

// ---------------------------------------------------------------------------
// MFMA flash attention, split-K=2, TJ=128 keys per softmax tile.
// grid (N/64, 2, B) linearized+swizzled; block 256 (4 waves).
// ---------------------------------------------------------------------------
__global__ __launch_bounds__(256) void attn_mfma(
    const u16* __restrict__ qt,   // (B,N,32) bf16
    const u16* __restrict__ kt,   // (B,N,32) bf16
    const u16* __restrict__ vb,   // (B,C,N) bf16
    float* __restrict__ Opart,    // (2,B,N,C) f32 unnormalized
    float* __restrict__ ml)       // [0:2BN) m, [2BN:4BN) l
{
  __shared__ __align__(16) u16  ps[2][64][136];   // P dbuf, pad 136 -> 68 KB
  __shared__ __align__(16) float als[2][64];

  const int tid  = threadIdx.x;
  const int lane = tid & 63;
  const int w    = tid >> 6;
  const int m    = lane & 15;
  const int quad = lane >> 4;

  const int lid = blockIdx.x + gridDim.x * (blockIdx.y + gridDim.y * blockIdx.z);
  const int grp = lid & 7;
  const int ksl = grp & 1;
  const int b   = grp >> 1;
  const int i0  = (lid >> 3) * 64;

  const bf16x8 qfrag =
      *(const bf16x8*)(qt + ((size_t)b * N_ + i0 + w * 16 + m) * C8_ + quad * 8);

  const u16* kbase = kt + (size_t)b * N_ * C8_;
  const u16* vrow  = vb + ((size_t)b * C_ + w * 64 + m) * N_;

  f32x4 o[4][4];
  #pragma unroll
  for (int t = 0; t < 4; ++t)
    #pragma unroll
    for (int ct = 0; ct < 4; ++ct) o[t][ct] = (f32x4){0.f, 0.f, 0.f, 0.f};
  float m_r = -1e30f, l_r = 0.f;

  const int jbeg = ksl * 2048, jend = jbeg + 2048;
  int buf = 0;

  for (int j0 = jbeg; j0 < jend; j0 += 128, buf ^= 1) {
    // K A-fragments (8 x 16 rows) and V B-fragments (4 ct x 4 kk)
    bf16x8 kA[8];
    #pragma unroll
    for (int t = 0; t < 8; ++t)
      kA[t] = *(const bf16x8*)(kbase + (size_t)(j0 + t * 16 + m) * C8_ + quad * 8);
    bf16x8 vB[4][4];
    #pragma unroll
    for (int ct = 0; ct < 4; ++ct)
      #pragma unroll
      for (int kk = 0; kk < 4; ++kk)
        vB[ct][kk] = *(const bf16x8*)(vrow + (size_t)ct * 16 * N_ + j0 + kk * 32 + quad * 8);

    // S^T[j][q]: 8 MFMAs
    f32x4 s[8];
    #pragma unroll
    for (int t = 0; t < 8; ++t)
      s[t] = __builtin_amdgcn_mfma_f32_16x16x32_bf16(
          kA[t], qfrag, (f32x4){0.f, 0.f, 0.f, 0.f}, 0, 0, 0);

    // register online softmax (lane owns query w*16+m across 32 j-values)
    float mx = -1e30f;
    #pragma unroll
    for (int t = 0; t < 8; ++t)
      #pragma unroll
      for (int r = 0; r < 4; ++r) mx = fmaxf(mx, s[t][r]);
    mx = fmaxf(mx, __shfl_xor(mx, 16));
    mx = fmaxf(mx, __shfl_xor(mx, 32));
    float mn = fmaxf(m_r, mx);
    float al = __expf(m_r - mn);
    m_r = mn;
    float p[8][4], sm = 0.f;
    #pragma unroll
    for (int t = 0; t < 8; ++t)
      #pragma unroll
      for (int r = 0; r < 4; ++r) {
        p[t][r] = __expf(s[t][r] - mn);
        sm += p[t][r];
      }
    sm += __shfl_xor(sm, 16);
    sm += __shfl_xor(sm, 32);
    l_r = l_r * al + sm;

    #pragma unroll
    for (int t = 0; t < 8; ++t) {
      u32 lo = (u32)f2bf(p[t][0]) | ((u32)f2bf(p[t][1]) << 16);
      u32 hi = (u32)f2bf(p[t][2]) | ((u32)f2bf(p[t][3]) << 16);
      *(uint2*)&ps[buf][w * 16 + m][t * 16 + quad * 4] = make_uint2(lo, hi);
    }
    if (quad == 0) als[buf][w * 16 + m] = al;

    __syncthreads();

    // rescale O by alphas
    #pragma unroll
    for (int t = 0; t < 4; ++t) {
      float4 alv = *(const float4*)&als[buf][t * 16 + quad * 4];
      #pragma unroll
      for (int ct = 0; ct < 4; ++ct) {
        o[t][ct][0] *= alv.x; o[t][ct][1] *= alv.y;
        o[t][ct][2] *= alv.z; o[t][ct][3] *= alv.w;
      }
    }

    // PV: O[64q x 64c-slice] += P[64 x 128] V^T[128 x 64]
    #pragma unroll
    for (int t = 0; t < 4; ++t) {
      #pragma unroll
      for (int kk = 0; kk < 4; ++kk) {
        bf16x8 pf = *(const bf16x8*)&ps[buf][t * 16 + m][kk * 32 + quad * 8];
        #pragma unroll
        for (int ct = 0; ct < 4; ++ct)
          o[t][ct] = __builtin_amdgcn_mfma_f32_16x16x32_bf16(pf, vB[ct][kk], o[t][ct], 0, 0, 0);
      }
    }
  }

  float* Ob = Opart + (size_t)ksl * B_ * N_ * C_ + ((size_t)b * N_ + i0) * C_ + w * 64;
  #pragma unroll
  for (int t = 0; t < 4; ++t)
    #pragma unroll
    for (int ct = 0; ct < 4; ++ct)
      #pragma unroll
      for (int r = 0; r < 4; ++r)
        Ob[(size_t)(t * 16 + quad * 4 + r) * C_ + ct * 16 + m] = o[t][ct][r];

  if (quad == 0) {
    size_t mli = ((size_t)ksl * B_ + b) * N_ + i0 + w * 16 + m;
    ml[mli] = m_r;
    ml[(size_t)2 * B_ * N_ + mli] = l_r;
  }
}

// ---------------------------------------------------------------------------
// Split-K combine: hb[b,n,c] = (O0*w0 + O1*w1)/l  -> bf16 (B,N,C)
// grid (N/64, B), block 256.
// ---------------------------------------------------------------------------
__global__ __launch_bounds__(256) void combine(
    const float* __restrict__ Opart, const float* __restrict__ ml,
    u16* __restrict__ hb)
{
  __shared__ __align__(16) u16 st[64][264];   // 33 KB
  const int tid = threadIdx.x;
  const int b   = blockIdx.y;
  const int n0  = blockIdx.x * 64;
  const int nl  = tid & 63;
  const int cg  = tid >> 6;

  size_t base = (size_t)b * N_ + n0 + nl;
  float m0 = ml[base];
  float m1 = ml[(size_t)B_ * N_ + base];
  float l0 = ml[(size_t)2 * B_ * N_ + base];
  float l1 = ml[(size_t)3 * B_ * N_ + base];
  float M  = fmaxf(m0, m1);
  float w0 = __expf(m0 - M), w1 = __expf(m1 - M);
  float inv = 1.f / (l0 * w0 + l1 * w1);
  w0 *= inv; w1 *= inv;

  const float* O0 = Opart + base * C_ + cg * 64;
  const float* O1 = O0 + (size_t)B_ * N_ * C_;
  #pragma unroll
  for (int cc = 0; cc < 64; cc += 4) {
    float4 a  = *(const float4*)(O0 + cc);
    float4 c2 = *(const float4*)(O1 + cc);
    u32 lo = (u32)f2bf(a.x * w0 + c2.x * w1) | ((u32)f2bf(a.y * w0 + c2.y * w1) << 16);
    u32 hi = (u32)f2bf(a.z * w0 + c2.z * w1) | ((u32)f2bf(a.w * w0 + c2.w * w1) << 16);
    *(uint2*)&st[nl][cg * 64 + cc] = make_uint2(lo, hi);
  }
  __syncthreads();

  #pragma unroll
  for (int it = 0; it < 8; ++it) {
    int idx = tid + it * 256;
    int n = idx >> 5, q = idx & 31;
    *(uint4*)&hb[((size_t)b * N_ + n0 + n) * C_ + q * 8] = *(const uint4*)&st[n][q * 8];
  }
}

// ---------------------------------------------------------------------------
// Final 1x1 conv with residual via linearity: out = Wo*h + Wo*x + bo
//   h (B,N,C) bf16, xT (B,N,C) bf16, Wo hi/lo split. out (B,C,N) f32.
// grid (N/64, B), block 256; wave w = d-range [64w, 64w+64).
// ---------------------------------------------------------------------------
__global__ __launch_bounds__(256) void out_mfma(
    const u16* __restrict__ hb, const u16* __restrict__ xT,
    const float* __restrict__ Wo, const float* __restrict__ bo,
    float* __restrict__ out)
{
  const int tid  = threadIdx.x;
  const int lane = tid & 63;
  const int w    = tid >> 6;
  const int m    = lane & 15;
  const int quad = lane >> 4;
  const int b    = blockIdx.y;
  const int n0   = blockIdx.x * 64;

  f32x4 o[4][4];
  #pragma unroll
  for (int dt = 0; dt < 4; ++dt)
    #pragma unroll
    for (int nt = 0; nt < 4; ++nt) o[dt][nt] = (f32x4){0.f, 0.f, 0.f, 0.f};

  for (int K = 0; K < 8; ++K) {
    bf16x8 hf[4], xf[4];
    #pragma unroll
    for (int nt = 0; nt < 4; ++nt) {
      size_t row = (size_t)b * N_ + n0 + nt * 16 + m;
      hf[nt] = *(const bf16x8*)(hb + row * C_ + K * 32 + quad * 8);
      xf[nt] = *(const bf16x8*)(xT + row * C_ + K * 32 + quad * 8);
    }
    #pragma unroll
    for (int dt = 0; dt < 4; ++dt) {
      bf16x8 whi, wlo;
      cvt8(Wo + (size_t)(64 * w + dt * 16 + m) * C_ + K * 32 + quad * 8, whi, wlo);
      #pragma unroll
      for (int nt = 0; nt < 4; ++nt) {
        o[dt][nt] = __builtin_amdgcn_mfma_f32_16x16x32_bf16(whi, hf[nt], o[dt][nt], 0, 0, 0);
        o[dt][nt] = __builtin_amdgcn_mfma_f32_16x16x32_bf16(wlo, hf[nt], o[dt][nt], 0, 0, 0);
        o[dt][nt] = __builtin_amdgcn_mfma_f32_16x16x32_bf16(whi, xf[nt], o[dt][nt], 0, 0, 0);
        o[dt][nt] = __builtin_amdgcn_mfma_f32_16x16x32_bf16(wlo, xf[nt], o[dt][nt], 0, 0, 0);
      }
    }
  }

  #pragma unroll
  for (int dt = 0; dt < 4; ++dt)
    #pragma unroll
    for (int r = 0; r < 4; ++r) {
      int d = 64 * w + dt * 16 + quad * 4 + r;
      float bias = bo[d];
      #pragma unroll
      for (int nt = 0; nt < 4; ++nt)
        out[((size_t)b * C_ + d) * N_ + n0 + nt * 16 + m] = o[dt][nt][r] + bias;
    }
}

// ---------------------------------------------------------------------------
extern "C" void kernel_launch(void* const* d_in, const int* in_sizes, int n_in,
                              void* d_out, int out_size, void* d_ws, size_t ws_size,
                              hipStream_t stream)
{
  const float* x  = (const float*)d_in[0];
  const float* Wq = (const float*)d_in[1];
  const float* bq = (const float*)d_in[2];
  const float* Wk = (const float*)d_in[3];
  const float* bk = (const float*)d_in[4];
  const float* Wv = (const float*)d_in[5];
  const float* bv = (const float*)d_in[6];
  const float* Wo = (const float*)d_in[7];
  const float* bo = (const float*)d_in[8];

  // workspace layout (~58.3 MB)
  u16* qt = (u16*)d_ws;                               // B*N*32 bf16 = 1 MB
  u16* kt = qt + (size_t)B_ * N_ * C8_;               // 1 MB
  u16* vb = kt + (size_t)B_ * N_ * C8_;               // 8 MB
  u16* hb = vb + (size_t)B_ * C_ * N_;                // 8 MB
  u16* xT = hb + (size_t)B_ * C_ * N_;                // 8 MB
  float* Opart = (float*)(xT + (size_t)B_ * N_ * C_); // 32 MB
  float* ml = Opart + (size_t)2 * B_ * N_ * C_;       // 256 KB

  float* out = (float*)d_out;

  qkv_mfma<<<dim3(N_ / 64, B_), 256, 0, stream>>>(
      x, Wq, bq, Wk, bk, Wv, bv, qt, kt, vb, xT);
  attn_mfma<<<dim3(N_ / 64, 2, B_), 256, 0, stream>>>(qt, kt, vb, Opart, ml);
  combine<<<dim3(N_ / 64, B_), 256, 0, stream>>>(Opart, ml, hb);
  out_mfma<<<dim3(N_ / 64, B_), 256, 0, stream>>>(hb, xT, Wo, bo, out);
}